// Round 9
// baseline (197.171 us; speedup 1.0000x reference)
//
#include <hip/hip_runtime.h>

// LSTM (B=8192, T=512, H=5) + MLP 5->32->32->5, fp32.
// Round 18: R17 with ALL sched_barrier fences removed — controlled A/B
// on the fencing itself.
//  - R17 post-mortem: packed-ALU cut landed exactly per the inst-count
//    law (wall -12), but exposed stall is still ~175 cyc. The fenced
//    windows carry only ~13 insts of fill vs ~100+ cyc of trans
//    latency (filler-starved, supply structurally fixed at 10 pk/step).
//  - Unexploited independent work exists OUTSIDE the windows: rdg
//    ds_reads, staging stores, loop arithmetic, cross-step overlap
//    (step t's DPP tail vs t+1's zx refills). SBAR fences pin all of
//    it out of the trans shadows. R13 measured fences ~neutral, but
//    that was pre-pk (485 vs 488); the mix has since changed -40%.
//  - This round: delete every SBAR(), change NOTHING else (math,
//    inst count, regs byte-identical). Any delta = pure scheduling.
//    Improvement -> fences were blocking, harvest further next round.
//    Flat -> in-order issue loss is inherent; wall floor ~= busy+170,
//    remaining levers are instruction count only.
//  - Keeps: packed activation ALU + cs pre-scale (R17), pk dots + A/B
//    zx slots (R16), 2-deep zx pipeline (R13), hrcp (R15 lesson),
//    freed allocator (R10), DPP broadcast (R9), LDS x-staging RSTR=164
//    (R8), pre-folded scales (R7).

#define LOG2E 1.44269504088896f

typedef float f32x2 __attribute__((ext_vector_type(2)));

__device__ __forceinline__ float hexp2(float x) { return __builtin_amdgcn_exp2f(x); }
__device__ __forceinline__ float hrcp(float x)  { return __builtin_amdgcn_rcpf(x); }

// packed fma with scalar-splat multiplicand: d = (a,a)*b + c
__device__ __forceinline__ f32x2 pk2(float a, f32x2 b, f32x2 c) {
  f32x2 av; av.x = a; av.y = a;
  return __builtin_elementwise_fma(av, b, c);
}

template<int CTRL>
__device__ __forceinline__ float dpp_mov(float x) {
  int r = __builtin_amdgcn_update_dpp(0, __builtin_bit_cast(int, x),
                                      CTRL, 0xF, 0xF, true);
  return __builtin_bit_cast(float, r);
}
template<int CTRL, int BANKMASK>
__device__ __forceinline__ float dpp_merge(float old, float src) {
  int r = __builtin_amdgcn_update_dpp(__builtin_bit_cast(int, old),
                                      __builtin_bit_cast(int, src),
                                      CTRL, 0xF, BANKMASK, false);
  return __builtin_bit_cast(float, r);
}

constexpr int TT   = 512;
constexpr int HD   = 5;
constexpr int RPB  = 8;     // rows per wave (8 lanes each)
constexpr int CHNK = 32;    // steps per LDS chunk
constexpr int RSTR = 164;   // padded LDS row stride
constexpr int XOFF = RPB * RSTR;
constexpr int NCH  = TT / CHNK;

__global__ __attribute__((amdgpu_flat_work_group_size(64, 64),
                          amdgpu_waves_per_eu(1, 1)))
void lstm_mlp_kernel(
    const float* __restrict__ x,   const float* __restrict__ Wih,
    const float* __restrict__ Whh, const float* __restrict__ bih,
    const float* __restrict__ bhh, const float* __restrict__ W1,
    const float* __restrict__ b1,  const float* __restrict__ W2,
    const float* __restrict__ b2,  const float* __restrict__ W3,
    const float* __restrict__ b3,  float* __restrict__ out, int B)
{
  const int lane = threadIdx.x;
  const int grp  = lane >> 3;           // row within block (0..7)
  const int j    = lane & 7;            // unit owned (valid if j<5)
  const int jj   = (j < 5) ? j : 0;
  const int blockRow = blockIdx.x * RPB;
  const int row  = blockRow + grp;
  const bool act = (j < 5) && (row < B);

  __shared__ __align__(16) float xbuf[2 * XOFF];
  __shared__ float s1[RPB][32];
  __shared__ float s2[RPB][32];

  // ---- per-lane weights, gate-PAIRED (x=gate0/2, y=gate1/3), pre-scaled --
  f32x2 wih01[5], wih23[5], whh01[5], whh23[5], bsum01, bsum23;
  {
    const float sA = -LOG2E, sG = 2.0f * LOG2E;
#pragma unroll
    for (int k = 0; k < 5; ++k) {
      wih01[k].x = Wih[(0 * 5 + jj) * 5 + k] * sA;
      wih01[k].y = Wih[(1 * 5 + jj) * 5 + k] * sA;
      wih23[k].x = Wih[(2 * 5 + jj) * 5 + k] * sG;
      wih23[k].y = Wih[(3 * 5 + jj) * 5 + k] * sA;
      whh01[k].x = Whh[(0 * 5 + jj) * 5 + k] * sA;
      whh01[k].y = Whh[(1 * 5 + jj) * 5 + k] * sA;
      whh23[k].x = Whh[(2 * 5 + jj) * 5 + k] * sG;
      whh23[k].y = Whh[(3 * 5 + jj) * 5 + k] * sA;
    }
    bsum01.x = (bih[0 * 5 + jj] + bhh[0 * 5 + jj]) * sA;
    bsum01.y = (bih[1 * 5 + jj] + bhh[1 * 5 + jj]) * sA;
    bsum23.x = (bih[2 * 5 + jj] + bhh[2 * 5 + jj]) * sG;
    bsum23.y = (bih[3 * 5 + jj] + bhh[3 * 5 + jj]) * sA;
  }

  const int rowc = (row < B) ? row : (B - 1);
  const float xl0 = x[(size_t)rowc * (TT * HD) + 511 * HD + 0];
  const float xl1 = x[(size_t)rowc * (TT * HD) + 511 * HD + 1];
  const float xl2 = x[(size_t)rowc * (TT * HD) + 511 * HD + 2];
  const float xl3 = x[(size_t)rowc * (TT * HD) + 511 * HD + 3];
  const float xl4 = x[(size_t)rowc * (TT * HD) + 511 * HD + 4];

  // ---- staging: 5x16B per lane per 32-step chunk (R8-proven) ----
  const float4* gp[5];
  int wa[5];
#pragma unroll
  for (int i = 0; i < 5; ++i) {
    int u  = i * 64 + lane;
    int r  = u / 40;
    int o4 = u - r * 40;
    int gr = blockRow + r; if (gr >= B) gr = B - 1;
    gp[i]  = (const float4*)(x + (size_t)gr * (TT * HD)) + o4;
    wa[i]  = r * RSTR + o4 * 4;
  }

  float4 st0, st1, st2, st3, st4;
  st0 = *gp[0]; gp[0] += 40; st1 = *gp[1]; gp[1] += 40;
  st2 = *gp[2]; gp[2] += 40; st3 = *gp[3]; gp[3] += 40;
  st4 = *gp[4]; gp[4] += 40;
  *(float4*)&xbuf[wa[0]] = st0; *(float4*)&xbuf[wa[1]] = st1;
  *(float4*)&xbuf[wa[2]] = st2; *(float4*)&xbuf[wa[3]] = st3;
  *(float4*)&xbuf[wa[4]] = st4;
  st0 = *gp[0]; gp[0] += 40; st1 = *gp[1]; gp[1] += 40;
  st2 = *gp[2]; gp[2] += 40; st3 = *gp[3]; gp[3] += 40;
  st4 = *gp[4]; gp[4] += 40;

  // ---- recurrence state ----
  float cs = 0.0f;   // pre-scaled cell state: cs = 2*LOG2E * c
  float hv0 = 0.f, hv1 = 0.f, hv2 = 0.f, hv3 = 0.f, hv4 = 0.f;
  // 2-deep x-part queue (paired): A = even steps, B = odd steps
  f32x2 zxA01, zxA23, zxB01, zxB23;

  // prologue: zx for steps 0 (->A) and 1 (->B) from chunk-0 buffer
  {
    const float* xp = &xbuf[grp * RSTR];
    zxA01 = bsum01; zxA23 = bsum23;
    zxA01 = pk2(xp[0], wih01[0], zxA01); zxA01 = pk2(xp[1], wih01[1], zxA01);
    zxA01 = pk2(xp[2], wih01[2], zxA01); zxA01 = pk2(xp[3], wih01[3], zxA01);
    zxA01 = pk2(xp[4], wih01[4], zxA01);
    zxA23 = pk2(xp[0], wih23[0], zxA23); zxA23 = pk2(xp[1], wih23[1], zxA23);
    zxA23 = pk2(xp[2], wih23[2], zxA23); zxA23 = pk2(xp[3], wih23[3], zxA23);
    zxA23 = pk2(xp[4], wih23[4], zxA23);
    zxB01 = bsum01; zxB23 = bsum23;
    zxB01 = pk2(xp[5], wih01[0], zxB01); zxB01 = pk2(xp[6], wih01[1], zxB01);
    zxB01 = pk2(xp[7], wih01[2], zxB01); zxB01 = pk2(xp[8], wih01[3], zxB01);
    zxB01 = pk2(xp[9], wih01[4], zxB01);
    zxB23 = pk2(xp[5], wih23[0], zxB23); zxB23 = pk2(xp[6], wih23[1], zxB23);
    zxB23 = pk2(xp[7], wih23[2], zxB23); zxB23 = pk2(xp[8], wih23[3], zxB23);
    zxB23 = pk2(xp[9], wih23[4], zxB23);
  }

  // pipelined step (NO fences — scheduler free): consumes zx (step t),
  // refills the same slot with the x-part of step t+2.
  auto stepCore = [&](f32x2& zx01, f32x2& zx23,
                      float n0, float n1, float n2, float n3, float n4) {
    // h-dots (chain head), packed across gate pairs, chains interleaved
    f32x2 z01 = zx01, z23 = zx23;
    z01 = pk2(hv0, whh01[0], z01); z23 = pk2(hv0, whh23[0], z23);
    z01 = pk2(hv1, whh01[1], z01); z23 = pk2(hv1, whh23[1], z23);
    z01 = pk2(hv2, whh01[2], z01); z23 = pk2(hv2, whh23[2], z23);
    z01 = pk2(hv3, whh01[3], z01); z23 = pk2(hv3, whh23[3], z23);
    z01 = pk2(hv4, whh01[4], z01); z23 = pk2(hv4, whh23[4], z23);
    // exps, g-gate first (heads the c-chain)
    f32x2 e01, e23;
    e23.x = hexp2(z23.x);
    e01.x = hexp2(z01.x);
    e01.y = hexp2(z01.y);
    e23.y = hexp2(z23.y);
    // x-part(t+2) fillers (scheduler places them)
    f32x2 n01 = bsum01, n23 = bsum23;
    n01 = pk2(n0, wih01[0], n01); n23 = pk2(n0, wih23[0], n23);
    n01 = pk2(n1, wih01[1], n01); n23 = pk2(n1, wih23[1], n23);
    // packed denominators + elementwise cross-product + 2 rcps
    f32x2 one2; one2.x = 1.0f; one2.y = 1.0f;
    f32x2 A01 = e01 + one2;          // (A0, A1)
    f32x2 A23 = e23 + one2;          // (A2, A3)
    f32x2 M   = A01 * A23;           // (A0*A2, A1*A3) = (m02, m13)
    float r02 = hrcp(M.x);
    float r13 = hrcp(M.y);
    float t2g2 = fmaf(2.0f * LOG2E, e23.x, -2.0f * LOG2E); // 2L*(A2-2)
    n01 = pk2(n2, wih01[2], n01); n23 = pk2(n2, wih23[2], n23);
    n01 = pk2(n3, wih01[3], n01); n23 = pk2(n3, wih23[3], n23);
    // gates + pre-scaled c-update + exp2(cs)  [cs = 2L*c]
    float igs = t2g2 * r02;          // 2L * i*g
    float fg  = A23.y * r13;         // f
    float og  = A01.y * r13;         // o
    cs = fmaf(fg, cs, igs);
    float ec = hexp2(cs);
    n01 = pk2(n4, wih01[4], n01); n23 = pk2(n4, wih23[4], n23);
    float o2 = og + og;
    // tanh(c) rcp
    float Ac = 1.0f + ec;
    float rc = hrcp(Ac);
    // h and broadcast (chain tail)
    float h = fmaf(-o2, rc, og);
    float q0 = dpp_mov<0x00>(h);
    float q1 = dpp_mov<0x55>(h);
    float q2 = dpp_mov<0xAA>(h);
    float q3 = dpp_mov<0xFF>(h);
    hv0 = dpp_merge<0x114, 0xA>(q0, q0);
    hv1 = dpp_merge<0x114, 0xA>(q1, q1);
    hv2 = dpp_merge<0x114, 0xA>(q2, q2);
    hv3 = dpp_merge<0x114, 0xA>(q3, q3);
    hv4 = dpp_merge<0x104, 0x5>(q0, q0);
    // refill the consumed slot with t+2's x-part (no rotation needed)
    zx01 = n01; zx23 = n23;
  };

  float4 A0v, A1v, A2v, A3v, A4v;
  float4 B0v, B1v, B2v, B3v, B4v;

  auto rdg = [&](int fi, float4& Av, float4& Bv, float4& Cv, float4& Dv, float4& Ev) {
    const float4* p = (const float4*)&xbuf[fi];
    Av = p[0]; Bv = p[1]; Cv = p[2]; Dv = p[3]; Ev = p[4];
  };

  // SUBA: steps a..a+3 (phase A,B,A,B); fillers = x(a+2..a+5)
  auto SUBA = [&]() {
    stepCore(zxA01, zxA23, A2v.z, A2v.w, A3v.x, A3v.y, A3v.z);
    stepCore(zxB01, zxB23, A3v.w, A4v.x, A4v.y, A4v.z, A4v.w);
    stepCore(zxA01, zxA23, B0v.x, B0v.y, B0v.z, B0v.w, B1v.x);
    stepCore(zxB01, zxB23, B1v.y, B1v.z, B1v.w, B2v.x, B2v.y);
  };
  // SUBB: steps b..b+3; fillers = x(b+2..b+5)
  auto SUBB = [&]() {
    stepCore(zxA01, zxA23, B2v.z, B2v.w, B3v.x, B3v.y, B3v.z);
    stepCore(zxB01, zxB23, B3v.w, B4v.x, B4v.y, B4v.z, B4v.w);
    stepCore(zxA01, zxA23, A0v.x, A0v.y, A0v.z, A0v.w, A1v.x);
    stepCore(zxB01, zxB23, A1v.y, A1v.z, A1v.w, A2v.x, A2v.y);
  };

#pragma unroll 1
  for (int ch = 0; ch < NCH; ++ch) {
    const int bo_cur  = (ch & 1) ? XOFF : 0;
    const int bo_next = XOFF - bo_cur;
    if (ch < NCH - 1) {
      *(float4*)&xbuf[wa[0] + bo_next] = st0;
      *(float4*)&xbuf[wa[1] + bo_next] = st1;
      *(float4*)&xbuf[wa[2] + bo_next] = st2;
      *(float4*)&xbuf[wa[3] + bo_next] = st3;
      *(float4*)&xbuf[wa[4] + bo_next] = st4;
    }
    if (ch < NCH - 2) {
      st0 = *gp[0]; gp[0] += 40; st1 = *gp[1]; gp[1] += 40;
      st2 = *gp[2]; gp[2] += 40; st3 = *gp[3]; gp[3] += 40;
      st4 = *gp[4]; gp[4] += 40;
    }
    const int xb = bo_cur + grp * RSTR;
    rdg(xb +   0, A0v, A1v, A2v, A3v, A4v);
    rdg(xb +  20, B0v, B1v, B2v, B3v, B4v);
    SUBA(); rdg(xb +  40, A0v, A1v, A2v, A3v, A4v);
    SUBB(); rdg(xb +  60, B0v, B1v, B2v, B3v, B4v);
    SUBA(); rdg(xb +  80, A0v, A1v, A2v, A3v, A4v);
    SUBB(); rdg(xb + 100, B0v, B1v, B2v, B3v, B4v);
    SUBA(); rdg(xb + 120, A0v, A1v, A2v, A3v, A4v);
    SUBB(); rdg(xb + 140, B0v, B1v, B2v, B3v, B4v);
    SUBA();
    // cross-chunk: next chunk's first group (dead values for last chunk)
    rdg(bo_next + grp * RSTR, A0v, A1v, A2v, A3v, A4v);
    SUBB();
  }

  // ---- MLP head (single wave; no barriers needed) ----
  float in5_0 = hv0 + xl0, in5_1 = hv1 + xl1, in5_2 = hv2 + xl2,
        in5_3 = hv3 + xl3, in5_4 = hv4 + xl4;

#pragma unroll
  for (int p = 0; p < 4; ++p) {
    int m = p * 8 + j;
    float acc = b1[m];
    acc = fmaf(W1[m * 5 + 0], in5_0, acc);
    acc = fmaf(W1[m * 5 + 1], in5_1, acc);
    acc = fmaf(W1[m * 5 + 2], in5_2, acc);
    acc = fmaf(W1[m * 5 + 3], in5_3, acc);
    acc = fmaf(W1[m * 5 + 4], in5_4, acc);
    s1[grp][m] = fmaxf(acc, 0.0f);
  }
  float y1[32];
#pragma unroll
  for (int k = 0; k < 32; ++k) y1[k] = s1[grp][k];

  auto dot32 = [&](const float* W, int m, const float* y, float b) {
    float acc = b;
    const float4* w4 = (const float4*)(W + m * 32);
#pragma unroll
    for (int k4 = 0; k4 < 8; ++k4) {
      float4 w = w4[k4];
      acc = fmaf(w.x, y[k4 * 4 + 0], acc);
      acc = fmaf(w.y, y[k4 * 4 + 1], acc);
      acc = fmaf(w.z, y[k4 * 4 + 2], acc);
      acc = fmaf(w.w, y[k4 * 4 + 3], acc);
    }
    return acc;
  };

#pragma unroll
  for (int p = 0; p < 4; ++p) {
    int m = p * 8 + j;
    s2[grp][m] = fmaxf(dot32(W2, m, y1, b2[m]), 0.0f);
  }
  float y2[32];
#pragma unroll
  for (int k = 0; k < 32; ++k) y2[k] = s2[grp][k];

  if (act) out[row * HD + j] = dot32(W3, j, y2, b3[j]);
}

extern "C" void kernel_launch(void* const* d_in, const int* in_sizes, int n_in,
                              void* d_out, int out_size, void* d_ws, size_t ws_size,
                              hipStream_t stream) {
  const float* x   = (const float*)d_in[0];
  const float* Wih = (const float*)d_in[1];
  const float* Whh = (const float*)d_in[2];
  const float* bih = (const float*)d_in[3];
  const float* bhh = (const float*)d_in[4];
  const float* W1  = (const float*)d_in[5];
  const float* b1  = (const float*)d_in[6];
  const float* W2  = (const float*)d_in[7];
  const float* b2  = (const float*)d_in[8];
  const float* W3  = (const float*)d_in[9];
  const float* b3  = (const float*)d_in[10];

  int B = in_sizes[0] / (TT * HD);
  int grid = (B + RPB - 1) / RPB;
  hipLaunchKernelGGL(lstm_mlp_kernel, dim3(grid), dim3(64), 0, stream,
                     x, Wih, Whh, bih, bhh, W1, b1, W2, b2, W3, b3,
                     (float*)d_out, B);
}

// Round 10
// 188.678 us; speedup vs baseline: 1.0450x; 1.0450x over previous
//
#include <hip/hip_runtime.h>

// LSTM (B=8192, T=512, H=5) + MLP 5->32->32->5, fp32.
// Round 19: filler redistribution into the DPP tail (placement-only).
//  - R18 A/B verdict: fences ~neutral -> in-order issue loss is
//    inherent; wall = busy(237) + exposure(~175). Filler supply is
//    fixed at 10 pk/step; max hiding ~20 cyc. Floor ~380-395 cyc.
//  - Waste found: the 9 dependent DPP ops run contiguously at the step
//    tail (VALU->DPP and DPP->DPP wait-states, ~50 cyc window with an
//    empty issue queue), while F1 over-fills the exp window that P3's
//    own ALU already covers.
//  - This round: SAME instructions, SAME math — only window placement:
//    F1: k0,k1 | F2: k2 | F3: k3 + o2 | F4: k4 moved INSIDE the
//    broadcast, between q-movs and merges (fills the hazard gap).
//  - Decision rule: flat (>=87) => structure floor reached; declare
//    next round.
//  - Keeps: packed activation ALU + cs pre-scale (R17), pk dots + A/B
//    zx slots (R16), fences + 2-deep zx pipeline (R13), hrcp (R15),
//    freed allocator (R10), DPP broadcast (R9), LDS x-staging RSTR=164
//    (R8), pre-folded scales (R7).

#define LOG2E 1.44269504088896f

typedef float f32x2 __attribute__((ext_vector_type(2)));

__device__ __forceinline__ float hexp2(float x) { return __builtin_amdgcn_exp2f(x); }
__device__ __forceinline__ float hrcp(float x)  { return __builtin_amdgcn_rcpf(x); }
#define SBAR() __builtin_amdgcn_sched_barrier(0)

// packed fma with scalar-splat multiplicand: d = (a,a)*b + c
__device__ __forceinline__ f32x2 pk2(float a, f32x2 b, f32x2 c) {
  f32x2 av; av.x = a; av.y = a;
  return __builtin_elementwise_fma(av, b, c);
}

template<int CTRL>
__device__ __forceinline__ float dpp_mov(float x) {
  int r = __builtin_amdgcn_update_dpp(0, __builtin_bit_cast(int, x),
                                      CTRL, 0xF, 0xF, true);
  return __builtin_bit_cast(float, r);
}
template<int CTRL, int BANKMASK>
__device__ __forceinline__ float dpp_merge(float old, float src) {
  int r = __builtin_amdgcn_update_dpp(__builtin_bit_cast(int, old),
                                      __builtin_bit_cast(int, src),
                                      CTRL, 0xF, BANKMASK, false);
  return __builtin_bit_cast(float, r);
}

constexpr int TT   = 512;
constexpr int HD   = 5;
constexpr int RPB  = 8;     // rows per wave (8 lanes each)
constexpr int CHNK = 32;    // steps per LDS chunk
constexpr int RSTR = 164;   // padded LDS row stride
constexpr int XOFF = RPB * RSTR;
constexpr int NCH  = TT / CHNK;

__global__ __attribute__((amdgpu_flat_work_group_size(64, 64),
                          amdgpu_waves_per_eu(1, 1)))
void lstm_mlp_kernel(
    const float* __restrict__ x,   const float* __restrict__ Wih,
    const float* __restrict__ Whh, const float* __restrict__ bih,
    const float* __restrict__ bhh, const float* __restrict__ W1,
    const float* __restrict__ b1,  const float* __restrict__ W2,
    const float* __restrict__ b2,  const float* __restrict__ W3,
    const float* __restrict__ b3,  float* __restrict__ out, int B)
{
  const int lane = threadIdx.x;
  const int grp  = lane >> 3;           // row within block (0..7)
  const int j    = lane & 7;            // unit owned (valid if j<5)
  const int jj   = (j < 5) ? j : 0;
  const int blockRow = blockIdx.x * RPB;
  const int row  = blockRow + grp;
  const bool act = (j < 5) && (row < B);

  __shared__ __align__(16) float xbuf[2 * XOFF];
  __shared__ float s1[RPB][32];
  __shared__ float s2[RPB][32];

  // ---- per-lane weights, gate-PAIRED (x=gate0/2, y=gate1/3), pre-scaled --
  f32x2 wih01[5], wih23[5], whh01[5], whh23[5], bsum01, bsum23;
  {
    const float sA = -LOG2E, sG = 2.0f * LOG2E;
#pragma unroll
    for (int k = 0; k < 5; ++k) {
      wih01[k].x = Wih[(0 * 5 + jj) * 5 + k] * sA;
      wih01[k].y = Wih[(1 * 5 + jj) * 5 + k] * sA;
      wih23[k].x = Wih[(2 * 5 + jj) * 5 + k] * sG;
      wih23[k].y = Wih[(3 * 5 + jj) * 5 + k] * sA;
      whh01[k].x = Whh[(0 * 5 + jj) * 5 + k] * sA;
      whh01[k].y = Whh[(1 * 5 + jj) * 5 + k] * sA;
      whh23[k].x = Whh[(2 * 5 + jj) * 5 + k] * sG;
      whh23[k].y = Whh[(3 * 5 + jj) * 5 + k] * sA;
    }
    bsum01.x = (bih[0 * 5 + jj] + bhh[0 * 5 + jj]) * sA;
    bsum01.y = (bih[1 * 5 + jj] + bhh[1 * 5 + jj]) * sA;
    bsum23.x = (bih[2 * 5 + jj] + bhh[2 * 5 + jj]) * sG;
    bsum23.y = (bih[3 * 5 + jj] + bhh[3 * 5 + jj]) * sA;
  }

  const int rowc = (row < B) ? row : (B - 1);
  const float xl0 = x[(size_t)rowc * (TT * HD) + 511 * HD + 0];
  const float xl1 = x[(size_t)rowc * (TT * HD) + 511 * HD + 1];
  const float xl2 = x[(size_t)rowc * (TT * HD) + 511 * HD + 2];
  const float xl3 = x[(size_t)rowc * (TT * HD) + 511 * HD + 3];
  const float xl4 = x[(size_t)rowc * (TT * HD) + 511 * HD + 4];

  // ---- staging: 5x16B per lane per 32-step chunk (R8-proven) ----
  const float4* gp[5];
  int wa[5];
#pragma unroll
  for (int i = 0; i < 5; ++i) {
    int u  = i * 64 + lane;
    int r  = u / 40;
    int o4 = u - r * 40;
    int gr = blockRow + r; if (gr >= B) gr = B - 1;
    gp[i]  = (const float4*)(x + (size_t)gr * (TT * HD)) + o4;
    wa[i]  = r * RSTR + o4 * 4;
  }

  float4 st0, st1, st2, st3, st4;
  st0 = *gp[0]; gp[0] += 40; st1 = *gp[1]; gp[1] += 40;
  st2 = *gp[2]; gp[2] += 40; st3 = *gp[3]; gp[3] += 40;
  st4 = *gp[4]; gp[4] += 40;
  *(float4*)&xbuf[wa[0]] = st0; *(float4*)&xbuf[wa[1]] = st1;
  *(float4*)&xbuf[wa[2]] = st2; *(float4*)&xbuf[wa[3]] = st3;
  *(float4*)&xbuf[wa[4]] = st4;
  st0 = *gp[0]; gp[0] += 40; st1 = *gp[1]; gp[1] += 40;
  st2 = *gp[2]; gp[2] += 40; st3 = *gp[3]; gp[3] += 40;
  st4 = *gp[4]; gp[4] += 40;

  // ---- recurrence state ----
  float cs = 0.0f;   // pre-scaled cell state: cs = 2*LOG2E * c
  float hv0 = 0.f, hv1 = 0.f, hv2 = 0.f, hv3 = 0.f, hv4 = 0.f;
  // 2-deep x-part queue (paired): A = even steps, B = odd steps
  f32x2 zxA01, zxA23, zxB01, zxB23;

  // prologue: zx for steps 0 (->A) and 1 (->B) from chunk-0 buffer
  {
    const float* xp = &xbuf[grp * RSTR];
    zxA01 = bsum01; zxA23 = bsum23;
    zxA01 = pk2(xp[0], wih01[0], zxA01); zxA01 = pk2(xp[1], wih01[1], zxA01);
    zxA01 = pk2(xp[2], wih01[2], zxA01); zxA01 = pk2(xp[3], wih01[3], zxA01);
    zxA01 = pk2(xp[4], wih01[4], zxA01);
    zxA23 = pk2(xp[0], wih23[0], zxA23); zxA23 = pk2(xp[1], wih23[1], zxA23);
    zxA23 = pk2(xp[2], wih23[2], zxA23); zxA23 = pk2(xp[3], wih23[3], zxA23);
    zxA23 = pk2(xp[4], wih23[4], zxA23);
    zxB01 = bsum01; zxB23 = bsum23;
    zxB01 = pk2(xp[5], wih01[0], zxB01); zxB01 = pk2(xp[6], wih01[1], zxB01);
    zxB01 = pk2(xp[7], wih01[2], zxB01); zxB01 = pk2(xp[8], wih01[3], zxB01);
    zxB01 = pk2(xp[9], wih01[4], zxB01);
    zxB23 = pk2(xp[5], wih23[0], zxB23); zxB23 = pk2(xp[6], wih23[1], zxB23);
    zxB23 = pk2(xp[7], wih23[2], zxB23); zxB23 = pk2(xp[8], wih23[3], zxB23);
    zxB23 = pk2(xp[9], wih23[4], zxB23);
  }

  // fenced pipelined step: consumes zx (step t), refills the same slot
  // with the x-part of step t+2. Filler windows: F1 exp | F2 rcp |
  // F3 exp2(cs) | F4 inside the DPP broadcast (hazard gap).
  auto stepCore = [&](f32x2& zx01, f32x2& zx23,
                      float n0, float n1, float n2, float n3, float n4) {
    // P1: h-dots (chain head), packed across gate pairs, interleaved
    f32x2 z01 = zx01, z23 = zx23;
    z01 = pk2(hv0, whh01[0], z01); z23 = pk2(hv0, whh23[0], z23);
    z01 = pk2(hv1, whh01[1], z01); z23 = pk2(hv1, whh23[1], z23);
    z01 = pk2(hv2, whh01[2], z01); z23 = pk2(hv2, whh23[2], z23);
    z01 = pk2(hv3, whh01[3], z01); z23 = pk2(hv3, whh23[3], z23);
    z01 = pk2(hv4, whh01[4], z01); z23 = pk2(hv4, whh23[4], z23);
    // P2: exps, g-gate first (heads the c-chain)
    f32x2 e01, e23;
    e23.x = hexp2(z23.x);
    e01.x = hexp2(z01.x);
    e01.y = hexp2(z01.y);
    e23.y = hexp2(z23.y);
    SBAR();
    // F1: x-part(t+2) k=0,1 — fills exp latency
    f32x2 n01 = bsum01, n23 = bsum23;
    n01 = pk2(n0, wih01[0], n01); n23 = pk2(n0, wih23[0], n23);
    n01 = pk2(n1, wih01[1], n01); n23 = pk2(n1, wih23[1], n23);
    SBAR();
    // P3: packed denominators + elementwise cross-product + 2 rcps
    f32x2 one2; one2.x = 1.0f; one2.y = 1.0f;
    f32x2 A01 = e01 + one2;          // (A0, A1)
    f32x2 A23 = e23 + one2;          // (A2, A3)
    f32x2 M   = A01 * A23;           // (A0*A2, A1*A3) = (m02, m13)
    float r02 = hrcp(M.x);
    float r13 = hrcp(M.y);
    float t2g2 = fmaf(2.0f * LOG2E, e23.x, -2.0f * LOG2E); // 2L*(A2-2)
    SBAR();
    // F2: x-part(t+2) k=2 — fills rcp latency
    n01 = pk2(n2, wih01[2], n01); n23 = pk2(n2, wih23[2], n23);
    SBAR();
    // P4: gates + pre-scaled c-update + exp2(cs)  [cs = 2L*c]
    float igs = t2g2 * r02;          // 2L * i*g
    float fg  = A23.y * r13;         // f
    float og  = A01.y * r13;         // o
    cs = fmaf(fg, cs, igs);
    float ec = hexp2(cs);
    SBAR();
    // F3: x-part(t+2) k=3 + 2*o — fills exp2(cs) latency
    n01 = pk2(n3, wih01[3], n01); n23 = pk2(n3, wih23[3], n23);
    float o2 = og + og;
    SBAR();
    // P5: tanh(c) rcp + h + q-movs
    float Ac = 1.0f + ec;
    float rc = hrcp(Ac);
    float h = fmaf(-o2, rc, og);
    float q0 = dpp_mov<0x00>(h);
    float q1 = dpp_mov<0x55>(h);
    float q2 = dpp_mov<0xAA>(h);
    float q3 = dpp_mov<0xFF>(h);
    SBAR();
    // F4: x-part(t+2) k=4 — fills the VALU->DPP / DPP->DPP hazard gap
    n01 = pk2(n4, wih01[4], n01); n23 = pk2(n4, wih23[4], n23);
    SBAR();
    // P6: merges (broadcast completion)
    hv0 = dpp_merge<0x114, 0xA>(q0, q0);
    hv1 = dpp_merge<0x114, 0xA>(q1, q1);
    hv2 = dpp_merge<0x114, 0xA>(q2, q2);
    hv3 = dpp_merge<0x114, 0xA>(q3, q3);
    hv4 = dpp_merge<0x104, 0x5>(q0, q0);
    // refill the consumed slot with t+2's x-part (no rotation needed)
    zx01 = n01; zx23 = n23;
  };

  float4 A0v, A1v, A2v, A3v, A4v;
  float4 B0v, B1v, B2v, B3v, B4v;

  auto rdg = [&](int fi, float4& Av, float4& Bv, float4& Cv, float4& Dv, float4& Ev) {
    const float4* p = (const float4*)&xbuf[fi];
    Av = p[0]; Bv = p[1]; Cv = p[2]; Dv = p[3]; Ev = p[4];
  };

  // SUBA: steps a..a+3 (phase A,B,A,B); fillers = x(a+2..a+5)
  auto SUBA = [&]() {
    stepCore(zxA01, zxA23, A2v.z, A2v.w, A3v.x, A3v.y, A3v.z);
    stepCore(zxB01, zxB23, A3v.w, A4v.x, A4v.y, A4v.z, A4v.w);
    stepCore(zxA01, zxA23, B0v.x, B0v.y, B0v.z, B0v.w, B1v.x);
    stepCore(zxB01, zxB23, B1v.y, B1v.z, B1v.w, B2v.x, B2v.y);
  };
  // SUBB: steps b..b+3; fillers = x(b+2..b+5)
  auto SUBB = [&]() {
    stepCore(zxA01, zxA23, B2v.z, B2v.w, B3v.x, B3v.y, B3v.z);
    stepCore(zxB01, zxB23, B3v.w, B4v.x, B4v.y, B4v.z, B4v.w);
    stepCore(zxA01, zxA23, A0v.x, A0v.y, A0v.z, A0v.w, A1v.x);
    stepCore(zxB01, zxB23, A1v.y, A1v.z, A1v.w, A2v.x, A2v.y);
  };

#pragma unroll 1
  for (int ch = 0; ch < NCH; ++ch) {
    const int bo_cur  = (ch & 1) ? XOFF : 0;
    const int bo_next = XOFF - bo_cur;
    if (ch < NCH - 1) {
      *(float4*)&xbuf[wa[0] + bo_next] = st0;
      *(float4*)&xbuf[wa[1] + bo_next] = st1;
      *(float4*)&xbuf[wa[2] + bo_next] = st2;
      *(float4*)&xbuf[wa[3] + bo_next] = st3;
      *(float4*)&xbuf[wa[4] + bo_next] = st4;
    }
    if (ch < NCH - 2) {
      st0 = *gp[0]; gp[0] += 40; st1 = *gp[1]; gp[1] += 40;
      st2 = *gp[2]; gp[2] += 40; st3 = *gp[3]; gp[3] += 40;
      st4 = *gp[4]; gp[4] += 40;
    }
    const int xb = bo_cur + grp * RSTR;
    rdg(xb +   0, A0v, A1v, A2v, A3v, A4v);
    rdg(xb +  20, B0v, B1v, B2v, B3v, B4v);
    SUBA(); rdg(xb +  40, A0v, A1v, A2v, A3v, A4v);
    SUBB(); rdg(xb +  60, B0v, B1v, B2v, B3v, B4v);
    SUBA(); rdg(xb +  80, A0v, A1v, A2v, A3v, A4v);
    SUBB(); rdg(xb + 100, B0v, B1v, B2v, B3v, B4v);
    SUBA(); rdg(xb + 120, A0v, A1v, A2v, A3v, A4v);
    SUBB(); rdg(xb + 140, B0v, B1v, B2v, B3v, B4v);
    SUBA();
    // cross-chunk: next chunk's first group (dead values for last chunk)
    rdg(bo_next + grp * RSTR, A0v, A1v, A2v, A3v, A4v);
    SUBB();
  }

  // ---- MLP head (single wave; no barriers needed) ----
  float in5_0 = hv0 + xl0, in5_1 = hv1 + xl1, in5_2 = hv2 + xl2,
        in5_3 = hv3 + xl3, in5_4 = hv4 + xl4;

#pragma unroll
  for (int p = 0; p < 4; ++p) {
    int m = p * 8 + j;
    float acc = b1[m];
    acc = fmaf(W1[m * 5 + 0], in5_0, acc);
    acc = fmaf(W1[m * 5 + 1], in5_1, acc);
    acc = fmaf(W1[m * 5 + 2], in5_2, acc);
    acc = fmaf(W1[m * 5 + 3], in5_3, acc);
    acc = fmaf(W1[m * 5 + 4], in5_4, acc);
    s1[grp][m] = fmaxf(acc, 0.0f);
  }
  float y1[32];
#pragma unroll
  for (int k = 0; k < 32; ++k) y1[k] = s1[grp][k];

  auto dot32 = [&](const float* W, int m, const float* y, float b) {
    float acc = b;
    const float4* w4 = (const float4*)(W + m * 32);
#pragma unroll
    for (int k4 = 0; k4 < 8; ++k4) {
      float4 w = w4[k4];
      acc = fmaf(w.x, y[k4 * 4 + 0], acc);
      acc = fmaf(w.y, y[k4 * 4 + 1], acc);
      acc = fmaf(w.z, y[k4 * 4 + 2], acc);
      acc = fmaf(w.w, y[k4 * 4 + 3], acc);
    }
    return acc;
  };

#pragma unroll
  for (int p = 0; p < 4; ++p) {
    int m = p * 8 + j;
    s2[grp][m] = fmaxf(dot32(W2, m, y1, b2[m]), 0.0f);
  }
  float y2[32];
#pragma unroll
  for (int k = 0; k < 32; ++k) y2[k] = s2[grp][k];

  if (act) out[row * HD + j] = dot32(W3, j, y2, b3[j]);
}

extern "C" void kernel_launch(void* const* d_in, const int* in_sizes, int n_in,
                              void* d_out, int out_size, void* d_ws, size_t ws_size,
                              hipStream_t stream) {
  const float* x   = (const float*)d_in[0];
  const float* Wih = (const float*)d_in[1];
  const float* Whh = (const float*)d_in[2];
  const float* bih = (const float*)d_in[3];
  const float* bhh = (const float*)d_in[4];
  const float* W1  = (const float*)d_in[5];
  const float* b1  = (const float*)d_in[6];
  const float* W2  = (const float*)d_in[7];
  const float* b2  = (const float*)d_in[8];
  const float* W3  = (const float*)d_in[9];
  const float* b3  = (const float*)d_in[10];

  int B = in_sizes[0] / (TT * HD);
  int grid = (B + RPB - 1) / RPB;
  hipLaunchKernelGGL(lstm_mlp_kernel, dim3(grid), dim3(64), 0, stream,
                     x, Wih, Whh, bih, bhh, W1, b1, W2, b2, W3, b3,
                     (float*)d_out, B);
}